// Round 4
// baseline (426.418 us; speedup 1.0000x reference)
//
#include <hip/hip_runtime.h>
#include <math.h>

#define BB   8
#define NN   2048
#define CINC 128
#define COU  256
#define KNNK 16
#define REVCAP 64
#define SEG   8
#define SEGC  (NN / SEG)   // 256 candidates per segment

// Compare-exchange on named u64 registers: after CX, a <= b.
#define CX(a, b) { unsigned long long _t = (a); bool _s = (b) < (a); \
                   (a) = _s ? (b) : _t; (b) = _s ? _t : (b); }

// 16 named sorted registers k0 <= k1 <= ... <= k15 (all-static accesses; no scratch).
#define KTOP_DECL \
    unsigned long long k0 = ~0ull, k1 = ~0ull, k2 = ~0ull, k3 = ~0ull,   \
                       k4 = ~0ull, k5 = ~0ull, k6 = ~0ull, k7 = ~0ull,   \
                       k8 = ~0ull, k9 = ~0ull, k10 = ~0ull, k11 = ~0ull, \
                       k12 = ~0ull, k13 = ~0ull, k14 = ~0ull, k15 = ~0ull;

#define KTOP_INSERT(key_) \
    if ((key_) < k15) {   \
        k15 = (key_);     \
        CX(k14, k15) CX(k13, k14) CX(k12, k13) CX(k11, k12) \
        CX(k10, k11) CX(k9, k10)  CX(k8, k9)   CX(k7, k8)   \
        CX(k6, k7)   CX(k5, k6)   CX(k4, k5)   CX(k3, k4)   \
        CX(k2, k3)   CX(k1, k2)   CX(k0, k1)                \
    }

// ---------------- transpose features (B,C,N) -> fT (B,N,C) ----------------
__global__ __launch_bounds__(256) void transpose_kernel(const float* __restrict__ feat,
                                                        float* __restrict__ fT) {
    __shared__ float t[32][33];
    int b  = blockIdx.z;
    int n0 = blockIdx.x * 32, c0 = blockIdx.y * 32;
    int tx = threadIdx.x, ty = threadIdx.y;  // (32,8)
#pragma unroll
    for (int i = 0; i < 4; i++)
        t[ty + i * 8][tx] = feat[((size_t)b * CINC + c0 + ty + i * 8) * NN + n0 + tx];
    __syncthreads();
#pragma unroll
    for (int i = 0; i < 4; i++)
        fT[((size_t)b * NN + n0 + ty + i * 8) * CINC + c0 + tx] = t[tx][ty + i * 8];
}

// ---------------- KNN part: per-lane register top-16 over one segment ----------------
// lane = query, wave = one segment of 256 candidates (staged in LDS, broadcast reads).
// Distance arithmetic bit-identical to the verified round-1 kernel:
//   sq  = (x*x + y*y) + z*z                 (plain rn ops, no FMA)
//   dot = fma(z,z', fma(y,y', rn(x*x')))    (FMA chain)
//   dist = (sq_n + sq_m) - 2*dot            (plain rn ops)
// Key = (ordered_float(dist) << 32) | idx : u64 lexicographic min == top_k tie-break.
__global__ __launch_bounds__(256) void knn_part_kernel(const float* __restrict__ xyz,
                                                       unsigned long long* __restrict__ part) {
    __shared__ float4 cand[4][SEGC];
    int b = blockIdx.z;
    int lane = threadIdx.x & 63;
    int w = threadIdx.x >> 6;                 // wave id -> segment
    int q = blockIdx.x * 64 + lane;
    int s = blockIdx.y * 4 + w;

    const float* xb = xyz + (size_t)b * 3 * NN;

    // stage 4 segments (1024 candidates) cooperatively
    int base = blockIdx.y * (4 * SEGC);
    for (int t = threadIdx.x; t < 4 * SEGC; t += 256) {
        int m = base + t;
        float x = xb[m], y = xb[NN + m], z = xb[2 * NN + m];
        float sq = __fadd_rn(__fadd_rn(__fmul_rn(x, x), __fmul_rn(y, y)), __fmul_rn(z, z));
        cand[t >> 8][t & (SEGC - 1)] = make_float4(x, y, z, sq);
    }
    __syncthreads();

    float qx = xb[q], qy = xb[NN + q], qz = xb[2 * NN + q];
    float qsq = __fadd_rn(__fadd_rn(__fmul_rn(qx, qx), __fmul_rn(qy, qy)), __fmul_rn(qz, qz));

    KTOP_DECL

    int segbase = s * SEGC;
    for (int i = 0; i < SEGC; i++) {
        float4 c = cand[w][i];
        float dot = fmaf(qz, c.z, fmaf(qy, c.y, __fmul_rn(qx, c.x)));
        float d = __fsub_rn(__fadd_rn(qsq, c.w), __fmul_rn(2.0f, dot));
        unsigned int u = __float_as_uint(d);
        u = ((int)u < 0) ? ~u : (u | 0x80000000u);
        unsigned long long key = ((unsigned long long)u << 32) | (unsigned int)(segbase + i);
        KTOP_INSERT(key)
    }

    unsigned long long* po = part + (((size_t)b * NN + q) * SEG + s) * KNNK;
    po[0] = k0;  po[1] = k1;  po[2] = k2;  po[3] = k3;
    po[4] = k4;  po[5] = k5;  po[6] = k6;  po[7] = k7;
    po[8] = k8;  po[9] = k9;  po[10] = k10; po[11] = k11;
    po[12] = k12; po[13] = k13; po[14] = k14; po[15] = k15;
}

// ---------------- KNN merge: fold 8 sorted 16-lists -> final top-16 ----------------
__global__ __launch_bounds__(256) void knn_merge_kernel(const unsigned long long* __restrict__ part,
                                                        int* __restrict__ knn_idx,
                                                        int* __restrict__ revcnt,
                                                        int* __restrict__ rev) {
    int bq = blockIdx.x * 256 + threadIdx.x;   // b*NN + n
    int b = bq >> 11;
    int n = bq & (NN - 1);

    KTOP_DECL

    const unsigned long long* pp = part + (size_t)bq * SEG * KNNK;
    for (int i = 0; i < SEG * KNNK; i++) {
        unsigned long long key = pp[i];
        KTOP_INSERT(key)
    }

    unsigned long long sel[16] = {k0, k1, k2, k3, k4, k5, k6, k7,
                                  k8, k9, k10, k11, k12, k13, k14, k15};
#pragma unroll
    for (int j = 0; j < 16; j++) {
        int m = (int)(sel[j] & 0xffffffffull);
        knn_idx[(size_t)bq * KNNK + j] = m;
        int pos = atomicAdd(&revcnt[b * NN + m], 1);
        if (pos < REVCAP) rev[((size_t)(b * NN + m)) * REVCAP + pos] = n;
    }
}

// ---------------- dinv = rsqrt(D + 1e-6), D = 0.5*(K + indeg) ----------------
__global__ __launch_bounds__(256) void dinv_kernel(const int* __restrict__ revcnt,
                                                   float* __restrict__ dinv) {
    int i = blockIdx.x * 256 + threadIdx.x;
    if (i < BB * NN) {
        float D = 0.5f * (float)(KNNK + revcnt[i]);
        dinv[i] = 1.0f / sqrtf(D + 1e-6f);
    }
}

// ---------------- spec[c,n] = f[c,n] - d_n * sum_j 0.5*d_mj * f[c,mj] ----------------
__global__ __launch_bounds__(128) void spec_kernel(const float* __restrict__ fT,
                                                   const int* __restrict__ knn_idx,
                                                   const int* __restrict__ revcnt,
                                                   const int* __restrict__ rev,
                                                   const float* __restrict__ dinv,
                                                   float* __restrict__ specT) {
    __shared__ int ml[KNNK + REVCAP];
    __shared__ float wl[KNNK + REVCAP];
    __shared__ int s_cnt;

    int bn = blockIdx.x;           // b*NN + n
    int b = bn >> 11;
    int tid = threadIdx.x;

    if (tid == 0) {
        int c = revcnt[bn];
        s_cnt = c < REVCAP ? c : REVCAP;
    }
    __syncthreads();
    int cnt = s_cnt;
    if (tid < KNNK) ml[tid] = knn_idx[(size_t)bn * KNNK + tid];
    if (tid < cnt) ml[KNNK + tid] = rev[(size_t)bn * REVCAP + tid];
    __syncthreads();
    int total = KNNK + cnt;
    if (tid < total) wl[tid] = 0.5f * dinv[b * NN + ml[tid]];
    __syncthreads();

    float dn = dinv[bn];
    float acc = 0.0f;
    for (int j = 0; j < total; j++)
        acc = fmaf(wl[j], fT[((size_t)b * NN + ml[j]) * CINC + tid], acc);
    float f0 = fT[(size_t)bn * CINC + tid];
    specT[(size_t)bn * CINC + tid] = f0 - dn * acc;
}

// ---------------- GEMM1: g1 = gelu(bn(W_spec @ spec + b)) , layout (b,n,o) ----------------
__global__ __launch_bounds__(256) void gemm1_kernel(const float* __restrict__ specT,
                                                    const float* __restrict__ Wspec,
                                                    const float* __restrict__ bspec,
                                                    const float* __restrict__ gamma,
                                                    const float* __restrict__ beta,
                                                    const float* __restrict__ mean,
                                                    const float* __restrict__ var,
                                                    float* __restrict__ g1T) {
    __shared__ float Sa[64][65];
    __shared__ float Sb[64][65];
    int n0 = blockIdx.x * 64, o0 = blockIdx.y * 64, b = blockIdx.z;
    int tx = threadIdx.x, ty = threadIdx.y;
    int tid = ty * 16 + tx;

    float acc[4][4] = {};
    for (int kk = 0; kk < CINC; kk += 64) {
        __syncthreads();
        for (int i = tid; i < 64 * 64; i += 256) {
            int r = i >> 6, k = i & 63;
            Sa[r][k] = specT[((size_t)b * NN + n0 + r) * CINC + kk + k];
            Sb[r][k] = Wspec[(size_t)(o0 + r) * CINC + kk + k];
        }
        __syncthreads();
#pragma unroll 8
        for (int k = 0; k < 64; k++) {
            float a0 = Sa[ty * 4 + 0][k], a1 = Sa[ty * 4 + 1][k];
            float a2 = Sa[ty * 4 + 2][k], a3 = Sa[ty * 4 + 3][k];
            float w0 = Sb[tx * 4 + 0][k], w1 = Sb[tx * 4 + 1][k];
            float w2 = Sb[tx * 4 + 2][k], w3 = Sb[tx * 4 + 3][k];
            acc[0][0] = fmaf(a0, w0, acc[0][0]); acc[0][1] = fmaf(a0, w1, acc[0][1]);
            acc[0][2] = fmaf(a0, w2, acc[0][2]); acc[0][3] = fmaf(a0, w3, acc[0][3]);
            acc[1][0] = fmaf(a1, w0, acc[1][0]); acc[1][1] = fmaf(a1, w1, acc[1][1]);
            acc[1][2] = fmaf(a1, w2, acc[1][2]); acc[1][3] = fmaf(a1, w3, acc[1][3]);
            acc[2][0] = fmaf(a2, w0, acc[2][0]); acc[2][1] = fmaf(a2, w1, acc[2][1]);
            acc[2][2] = fmaf(a2, w2, acc[2][2]); acc[2][3] = fmaf(a2, w3, acc[2][3]);
            acc[3][0] = fmaf(a3, w0, acc[3][0]); acc[3][1] = fmaf(a3, w1, acc[3][1]);
            acc[3][2] = fmaf(a3, w2, acc[3][2]); acc[3][3] = fmaf(a3, w3, acc[3][3]);
        }
    }
#pragma unroll
    for (int j = 0; j < 4; j++) {
        int o = o0 + tx * 4 + j;
        float sc = 1.0f / sqrtf(var[o] + 1e-5f);
        float ga = gamma[o], be = beta[o], mu = mean[o], bs = bspec[o];
#pragma unroll
        for (int i = 0; i < 4; i++) {
            float y = acc[i][j] + bs;
            y = (y - mu) * sc;
            y = y * ga + be;
            float g = 0.5f * y * (1.0f + erff(y * 0.70710678118654752440f));
            g1T[((size_t)b * NN + n0 + ty * 4 + i) * COU + o] = g;
        }
    }
}

// ---------------- GEMM2: out[b,o,n] = W2[o,:] @ g1[b,n,:] + b2[o] ----------------
__global__ __launch_bounds__(256) void gemm2_kernel(const float* __restrict__ g1T,
                                                    const float* __restrict__ Wlow,
                                                    const float* __restrict__ blow,
                                                    const float* __restrict__ Whigh,
                                                    const float* __restrict__ bhigh,
                                                    float* __restrict__ out) {
    __shared__ float Ga[64][65];
    __shared__ float Wb[64][65];
    int n0 = blockIdx.x * 64, o0 = blockIdx.y * 64, b = blockIdx.z;
    int tx = threadIdx.x, ty = threadIdx.y;
    int tid = ty * 16 + tx;

    float acc[4][4] = {};
    for (int kk = 0; kk < COU; kk += 64) {
        __syncthreads();
        for (int i = tid; i < 64 * 64; i += 256) {
            int r = i >> 6, k = i & 63;
            Ga[r][k] = g1T[((size_t)b * NN + n0 + r) * COU + kk + k];
            int o = o0 + r;
            Wb[r][k] = (o < 128) ? Wlow[(size_t)o * COU + kk + k]
                                 : Whigh[(size_t)(o - 128) * COU + kk + k];
        }
        __syncthreads();
#pragma unroll 8
        for (int k = 0; k < 64; k++) {
            float a0 = Ga[ty * 4 + 0][k], a1 = Ga[ty * 4 + 1][k];
            float a2 = Ga[ty * 4 + 2][k], a3 = Ga[ty * 4 + 3][k];
            float w0 = Wb[tx * 4 + 0][k], w1 = Wb[tx * 4 + 1][k];
            float w2 = Wb[tx * 4 + 2][k], w3 = Wb[tx * 4 + 3][k];
            acc[0][0] = fmaf(a0, w0, acc[0][0]); acc[0][1] = fmaf(a0, w1, acc[0][1]);
            acc[0][2] = fmaf(a0, w2, acc[0][2]); acc[0][3] = fmaf(a0, w3, acc[0][3]);
            acc[1][0] = fmaf(a1, w0, acc[1][0]); acc[1][1] = fmaf(a1, w1, acc[1][1]);
            acc[1][2] = fmaf(a1, w2, acc[1][2]); acc[1][3] = fmaf(a1, w3, acc[1][3]);
            acc[2][0] = fmaf(a2, w0, acc[2][0]); acc[2][1] = fmaf(a2, w1, acc[2][1]);
            acc[2][2] = fmaf(a2, w2, acc[2][2]); acc[2][3] = fmaf(a2, w3, acc[2][3]);
            acc[3][0] = fmaf(a3, w0, acc[3][0]); acc[3][1] = fmaf(a3, w1, acc[3][1]);
            acc[3][2] = fmaf(a3, w2, acc[3][2]); acc[3][3] = fmaf(a3, w3, acc[3][3]);
        }
    }
#pragma unroll
    for (int j = 0; j < 4; j++) {
        int o = o0 + tx * 4 + j;
        float bias = (o < 128) ? blow[o] : bhigh[o - 128];
        float4 v;
        v.x = acc[0][j] + bias;
        v.y = acc[1][j] + bias;
        v.z = acc[2][j] + bias;
        v.w = acc[3][j] + bias;
        *(float4*)&out[((size_t)b * COU + o) * NN + n0 + ty * 4] = v;
    }
}

extern "C" void kernel_launch(void* const* d_in, const int* in_sizes, int n_in,
                              void* d_out, int out_size, void* d_ws, size_t ws_size,
                              hipStream_t stream) {
    const float* xyz      = (const float*)d_in[0];
    const float* features = (const float*)d_in[1];
    const float* W_spec   = (const float*)d_in[2];
    const float* b_spec   = (const float*)d_in[3];
    const float* bn_gamma = (const float*)d_in[4];
    const float* bn_beta  = (const float*)d_in[5];
    const float* bn_mean  = (const float*)d_in[6];
    const float* bn_var   = (const float*)d_in[7];
    const float* W_low    = (const float*)d_in[8];
    const float* b_low    = (const float*)d_in[9];
    const float* W_high   = (const float*)d_in[10];
    const float* b_high   = (const float*)d_in[11];
    float* out = (float*)d_out;

    char* ws = (char*)d_ws;
    size_t off = 0;
    float* fT    = (float*)(ws + off); off += (size_t)BB * NN * CINC * 4;            // 8 MB
    float* specT = (float*)(ws + off); off += (size_t)BB * NN * CINC * 4;            // 8 MB
    float* g1T   = (float*)(ws + off); off += (size_t)BB * NN * COU  * 4;            // 16 MB
    int*   idx   = (int*)  (ws + off); off += (size_t)BB * NN * KNNK * 4;            // 1 MB
    int*   rcnt  = (int*)  (ws + off); off += (size_t)BB * NN * 4;                   // 64 KB
    int*   rev   = (int*)  (ws + off); off += (size_t)BB * NN * REVCAP * 4;          // 4 MB
    float* dinv  = (float*)(ws + off); off += (size_t)BB * NN * 4;                   // 64 KB
    unsigned long long* part = (unsigned long long*)(ws + off);
    off += (size_t)BB * NN * SEG * KNNK * 8;                                         // 16 MB

    hipMemsetAsync(rcnt, 0, (size_t)BB * NN * sizeof(int), stream);

    transpose_kernel<<<dim3(NN / 32, CINC / 32, BB), dim3(32, 8), 0, stream>>>(features, fT);
    knn_part_kernel<<<dim3(NN / 64, SEG / 4, BB), dim3(256), 0, stream>>>(xyz, part);
    knn_merge_kernel<<<dim3(BB * NN / 256), dim3(256), 0, stream>>>(part, idx, rcnt, rev);
    dinv_kernel<<<dim3(BB * NN / 256), dim3(256), 0, stream>>>(rcnt, dinv);
    spec_kernel<<<dim3(BB * NN), dim3(128), 0, stream>>>(fT, idx, rcnt, rev, dinv, specT);
    gemm1_kernel<<<dim3(NN / 64, COU / 64, BB), dim3(16, 16), 0, stream>>>(
        specT, W_spec, b_spec, bn_gamma, bn_beta, bn_mean, bn_var, g1T);
    gemm2_kernel<<<dim3(NN / 64, COU / 64, BB), dim3(16, 16), 0, stream>>>(
        g1T, W_low, b_low, W_high, b_high, out);
}

// Round 5
// 324.676 us; speedup vs baseline: 1.3134x; 1.3134x over previous
//
#include <hip/hip_runtime.h>
#include <math.h>

#define BB   8
#define NN   2048
#define CINC 128
#define COU  256
#define KNNK 16
#define REVCAP 64
#define SEG   8
#define SEGC  (NN / SEG)   // 256 candidates per segment

#define U64MIN(a, b) (((a) < (b)) ? (a) : (b))
#define U64MAX(a, b) (((a) > (b)) ? (a) : (b))

// 16 named sorted registers k0 <= k1 <= ... <= k15.
#define KTOP_DECL \
    unsigned long long k0 = ~0ull, k1 = ~0ull, k2 = ~0ull, k3 = ~0ull,   \
                       k4 = ~0ull, k5 = ~0ull, k6 = ~0ull, k7 = ~0ull,   \
                       k8 = ~0ull, k9 = ~0ull, k10 = ~0ull, k11 = ~0ull, \
                       k12 = ~0ull, k13 = ~0ull, k14 = ~0ull, k15 = ~0ull;

// Branch-free sorted insert (drops old max). Descending j uses old k_{j-1}
// (not yet overwritten) and old k_j (being overwritten): k_j = max(k_{j-1}, min(k_j, key)).
// If key >= k15 this is a provable no-op. Depth-2 dataflow, no divergence.
#define KTOP_INSERT(key_) {                                        \
    k15 = U64MAX(k14, U64MIN(k15, (key_)));                        \
    k14 = U64MAX(k13, U64MIN(k14, (key_)));                        \
    k13 = U64MAX(k12, U64MIN(k13, (key_)));                        \
    k12 = U64MAX(k11, U64MIN(k12, (key_)));                        \
    k11 = U64MAX(k10, U64MIN(k11, (key_)));                        \
    k10 = U64MAX(k9,  U64MIN(k10, (key_)));                        \
    k9  = U64MAX(k8,  U64MIN(k9,  (key_)));                        \
    k8  = U64MAX(k7,  U64MIN(k8,  (key_)));                        \
    k7  = U64MAX(k6,  U64MIN(k7,  (key_)));                        \
    k6  = U64MAX(k5,  U64MIN(k6,  (key_)));                        \
    k5  = U64MAX(k4,  U64MIN(k5,  (key_)));                        \
    k4  = U64MAX(k3,  U64MIN(k4,  (key_)));                        \
    k3  = U64MAX(k2,  U64MIN(k3,  (key_)));                        \
    k2  = U64MAX(k1,  U64MIN(k2,  (key_)));                        \
    k1  = U64MAX(k0,  U64MIN(k1,  (key_)));                        \
    k0  = U64MIN(k0, (key_));                                      \
}

// ---------------- transpose features (B,C,N) -> fT (B,N,C) ----------------
__global__ __launch_bounds__(256) void transpose_kernel(const float* __restrict__ feat,
                                                        float* __restrict__ fT) {
    __shared__ float t[32][33];
    int b  = blockIdx.z;
    int n0 = blockIdx.x * 32, c0 = blockIdx.y * 32;
    int tx = threadIdx.x, ty = threadIdx.y;  // (32,8)
#pragma unroll
    for (int i = 0; i < 4; i++)
        t[ty + i * 8][tx] = feat[((size_t)b * CINC + c0 + ty + i * 8) * NN + n0 + tx];
    __syncthreads();
#pragma unroll
    for (int i = 0; i < 4; i++)
        fT[((size_t)b * NN + n0 + ty + i * 8) * CINC + c0 + tx] = t[tx][ty + i * 8];
}

// ---------------- KNN part: per-lane register top-16 over one segment ----------------
// lane = query, wave = one segment of 256 candidates (staged in LDS, broadcast reads).
// Distance arithmetic bit-identical to the verified round-1 kernel:
//   sq  = (x*x + y*y) + z*z                 (plain rn ops, no FMA)
//   dot = fma(z,z', fma(y,y', rn(x*x')))    (FMA chain)
//   dist = (sq_n + sq_m) - 2*dot            (plain rn ops)
// Key = (ordered_float(dist) << 32) | idx : u64 lexicographic min == top_k tie-break.
__global__ __launch_bounds__(256) void knn_part_kernel(const float* __restrict__ xyz,
                                                       unsigned long long* __restrict__ part) {
    __shared__ float4 cand[4][SEGC];
    int b = blockIdx.z;
    int lane = threadIdx.x & 63;
    int w = threadIdx.x >> 6;                 // wave id -> segment
    int q = blockIdx.x * 64 + lane;
    int s = blockIdx.y * 4 + w;

    const float* xb = xyz + (size_t)b * 3 * NN;

    // stage 4 segments (1024 candidates) cooperatively
    int base = blockIdx.y * (4 * SEGC);
    for (int t = threadIdx.x; t < 4 * SEGC; t += 256) {
        int m = base + t;
        float x = xb[m], y = xb[NN + m], z = xb[2 * NN + m];
        float sq = __fadd_rn(__fadd_rn(__fmul_rn(x, x), __fmul_rn(y, y)), __fmul_rn(z, z));
        cand[t >> 8][t & (SEGC - 1)] = make_float4(x, y, z, sq);
    }
    __syncthreads();

    float qx = xb[q], qy = xb[NN + q], qz = xb[2 * NN + q];
    float qsq = __fadd_rn(__fadd_rn(__fmul_rn(qx, qx), __fmul_rn(qy, qy)), __fmul_rn(qz, qz));

    KTOP_DECL

    int segbase = s * SEGC;
    for (int i = 0; i < SEGC; i++) {
        float4 c = cand[w][i];
        float dot = fmaf(qz, c.z, fmaf(qy, c.y, __fmul_rn(qx, c.x)));
        float d = __fsub_rn(__fadd_rn(qsq, c.w), __fmul_rn(2.0f, dot));
        unsigned int u = __float_as_uint(d);
        u = ((int)u < 0) ? ~u : (u | 0x80000000u);
        unsigned long long key = ((unsigned long long)u << 32) | (unsigned int)(segbase + i);
        KTOP_INSERT(key)
    }

    unsigned long long* po = part + (((size_t)b * NN + q) * SEG + s) * KNNK;
    po[0] = k0;  po[1] = k1;  po[2] = k2;  po[3] = k3;
    po[4] = k4;  po[5] = k5;  po[6] = k6;  po[7] = k7;
    po[8] = k8;  po[9] = k9;  po[10] = k10; po[11] = k11;
    po[12] = k12; po[13] = k13; po[14] = k14; po[15] = k15;
}

// ---------------- KNN merge: fold 8 sorted 16-lists -> final top-16 ----------------
__global__ __launch_bounds__(256) void knn_merge_kernel(const unsigned long long* __restrict__ part,
                                                        int* __restrict__ knn_idx,
                                                        int* __restrict__ revcnt,
                                                        int* __restrict__ rev) {
    int bq = blockIdx.x * 256 + threadIdx.x;   // b*NN + n
    int b = bq >> 11;
    int n = bq & (NN - 1);

    KTOP_DECL

    const unsigned long long* pp = part + (size_t)bq * SEG * KNNK;
    for (int i = 0; i < SEG * KNNK; i++) {
        unsigned long long key = pp[i];
        KTOP_INSERT(key)
    }

#define EMIT(j_, kreg_) {                                              \
        int m = (int)((kreg_) & 0xffffffffull);                        \
        knn_idx[(size_t)bq * KNNK + (j_)] = m;                         \
        int pos = atomicAdd(&revcnt[b * NN + m], 1);                   \
        if (pos < REVCAP) rev[((size_t)(b * NN + m)) * REVCAP + pos] = n; \
    }
    EMIT(0, k0)   EMIT(1, k1)   EMIT(2, k2)   EMIT(3, k3)
    EMIT(4, k4)   EMIT(5, k5)   EMIT(6, k6)   EMIT(7, k7)
    EMIT(8, k8)   EMIT(9, k9)   EMIT(10, k10) EMIT(11, k11)
    EMIT(12, k12) EMIT(13, k13) EMIT(14, k14) EMIT(15, k15)
#undef EMIT
}

// ---------------- dinv = rsqrt(D + 1e-6), D = 0.5*(K + indeg) ----------------
__global__ __launch_bounds__(256) void dinv_kernel(const int* __restrict__ revcnt,
                                                   float* __restrict__ dinv) {
    int i = blockIdx.x * 256 + threadIdx.x;
    if (i < BB * NN) {
        float D = 0.5f * (float)(KNNK + revcnt[i]);
        dinv[i] = 1.0f / sqrtf(D + 1e-6f);
    }
}

// ---------------- spec[c,n] = f[c,n] - d_n * sum_j 0.5*d_mj * f[c,mj] ----------------
__global__ __launch_bounds__(128) void spec_kernel(const float* __restrict__ fT,
                                                   const int* __restrict__ knn_idx,
                                                   const int* __restrict__ revcnt,
                                                   const int* __restrict__ rev,
                                                   const float* __restrict__ dinv,
                                                   float* __restrict__ specT) {
    __shared__ int ml[KNNK + REVCAP];
    __shared__ float wl[KNNK + REVCAP];
    __shared__ int s_cnt;

    int bn = blockIdx.x;           // b*NN + n
    int b = bn >> 11;
    int tid = threadIdx.x;

    if (tid == 0) {
        int c = revcnt[bn];
        s_cnt = c < REVCAP ? c : REVCAP;
    }
    __syncthreads();
    int cnt = s_cnt;
    if (tid < KNNK) ml[tid] = knn_idx[(size_t)bn * KNNK + tid];
    if (tid < cnt) ml[KNNK + tid] = rev[(size_t)bn * REVCAP + tid];
    __syncthreads();
    int total = KNNK + cnt;
    if (tid < total) wl[tid] = 0.5f * dinv[b * NN + ml[tid]];
    __syncthreads();

    float dn = dinv[bn];
    float acc = 0.0f;
    for (int j = 0; j < total; j++)
        acc = fmaf(wl[j], fT[((size_t)b * NN + ml[j]) * CINC + tid], acc);
    float f0 = fT[(size_t)bn * CINC + tid];
    specT[(size_t)bn * CINC + tid] = f0 - dn * acc;
}

// ---------------- GEMM1: g1 = gelu(bn(W_spec @ spec + b)) , layout (b,n,o) ----------------
__global__ __launch_bounds__(256) void gemm1_kernel(const float* __restrict__ specT,
                                                    const float* __restrict__ Wspec,
                                                    const float* __restrict__ bspec,
                                                    const float* __restrict__ gamma,
                                                    const float* __restrict__ beta,
                                                    const float* __restrict__ mean,
                                                    const float* __restrict__ var,
                                                    float* __restrict__ g1T) {
    __shared__ float Sa[64][65];
    __shared__ float Sb[64][65];
    int n0 = blockIdx.x * 64, o0 = blockIdx.y * 64, b = blockIdx.z;
    int tx = threadIdx.x, ty = threadIdx.y;
    int tid = ty * 16 + tx;

    float acc[4][4] = {};
    for (int kk = 0; kk < CINC; kk += 64) {
        __syncthreads();
        for (int i = tid; i < 64 * 64; i += 256) {
            int r = i >> 6, k = i & 63;
            Sa[r][k] = specT[((size_t)b * NN + n0 + r) * CINC + kk + k];
            Sb[r][k] = Wspec[(size_t)(o0 + r) * CINC + kk + k];
        }
        __syncthreads();
#pragma unroll 8
        for (int k = 0; k < 64; k++) {
            float a0 = Sa[ty * 4 + 0][k], a1 = Sa[ty * 4 + 1][k];
            float a2 = Sa[ty * 4 + 2][k], a3 = Sa[ty * 4 + 3][k];
            float w0 = Sb[tx * 4 + 0][k], w1 = Sb[tx * 4 + 1][k];
            float w2 = Sb[tx * 4 + 2][k], w3 = Sb[tx * 4 + 3][k];
            acc[0][0] = fmaf(a0, w0, acc[0][0]); acc[0][1] = fmaf(a0, w1, acc[0][1]);
            acc[0][2] = fmaf(a0, w2, acc[0][2]); acc[0][3] = fmaf(a0, w3, acc[0][3]);
            acc[1][0] = fmaf(a1, w0, acc[1][0]); acc[1][1] = fmaf(a1, w1, acc[1][1]);
            acc[1][2] = fmaf(a1, w2, acc[1][2]); acc[1][3] = fmaf(a1, w3, acc[1][3]);
            acc[2][0] = fmaf(a2, w0, acc[2][0]); acc[2][1] = fmaf(a2, w1, acc[2][1]);
            acc[2][2] = fmaf(a2, w2, acc[2][2]); acc[2][3] = fmaf(a2, w3, acc[2][3]);
            acc[3][0] = fmaf(a3, w0, acc[3][0]); acc[3][1] = fmaf(a3, w1, acc[3][1]);
            acc[3][2] = fmaf(a3, w2, acc[3][2]); acc[3][3] = fmaf(a3, w3, acc[3][3]);
        }
    }
#pragma unroll
    for (int j = 0; j < 4; j++) {
        int o = o0 + tx * 4 + j;
        float sc = 1.0f / sqrtf(var[o] + 1e-5f);
        float ga = gamma[o], be = beta[o], mu = mean[o], bs = bspec[o];
#pragma unroll
        for (int i = 0; i < 4; i++) {
            float y = acc[i][j] + bs;
            y = (y - mu) * sc;
            y = y * ga + be;
            float g = 0.5f * y * (1.0f + erff(y * 0.70710678118654752440f));
            g1T[((size_t)b * NN + n0 + ty * 4 + i) * COU + o] = g;
        }
    }
}

// ---------------- GEMM2: out[b,o,n] = W2[o,:] @ g1[b,n,:] + b2[o] ----------------
__global__ __launch_bounds__(256) void gemm2_kernel(const float* __restrict__ g1T,
                                                    const float* __restrict__ Wlow,
                                                    const float* __restrict__ blow,
                                                    const float* __restrict__ Whigh,
                                                    const float* __restrict__ bhigh,
                                                    float* __restrict__ out) {
    __shared__ float Ga[64][65];
    __shared__ float Wb[64][65];
    int n0 = blockIdx.x * 64, o0 = blockIdx.y * 64, b = blockIdx.z;
    int tx = threadIdx.x, ty = threadIdx.y;
    int tid = ty * 16 + tx;

    float acc[4][4] = {};
    for (int kk = 0; kk < COU; kk += 64) {
        __syncthreads();
        for (int i = tid; i < 64 * 64; i += 256) {
            int r = i >> 6, k = i & 63;
            Ga[r][k] = g1T[((size_t)b * NN + n0 + r) * COU + kk + k];
            int o = o0 + r;
            Wb[r][k] = (o < 128) ? Wlow[(size_t)o * COU + kk + k]
                                 : Whigh[(size_t)(o - 128) * COU + kk + k];
        }
        __syncthreads();
#pragma unroll 8
        for (int k = 0; k < 64; k++) {
            float a0 = Ga[ty * 4 + 0][k], a1 = Ga[ty * 4 + 1][k];
            float a2 = Ga[ty * 4 + 2][k], a3 = Ga[ty * 4 + 3][k];
            float w0 = Wb[tx * 4 + 0][k], w1 = Wb[tx * 4 + 1][k];
            float w2 = Wb[tx * 4 + 2][k], w3 = Wb[tx * 4 + 3][k];
            acc[0][0] = fmaf(a0, w0, acc[0][0]); acc[0][1] = fmaf(a0, w1, acc[0][1]);
            acc[0][2] = fmaf(a0, w2, acc[0][2]); acc[0][3] = fmaf(a0, w3, acc[0][3]);
            acc[1][0] = fmaf(a1, w0, acc[1][0]); acc[1][1] = fmaf(a1, w1, acc[1][1]);
            acc[1][2] = fmaf(a1, w2, acc[1][2]); acc[1][3] = fmaf(a1, w3, acc[1][3]);
            acc[2][0] = fmaf(a2, w0, acc[2][0]); acc[2][1] = fmaf(a2, w1, acc[2][1]);
            acc[2][2] = fmaf(a2, w2, acc[2][2]); acc[2][3] = fmaf(a2, w3, acc[2][3]);
            acc[3][0] = fmaf(a3, w0, acc[3][0]); acc[3][1] = fmaf(a3, w1, acc[3][1]);
            acc[3][2] = fmaf(a3, w2, acc[3][2]); acc[3][3] = fmaf(a3, w3, acc[3][3]);
        }
    }
#pragma unroll
    for (int j = 0; j < 4; j++) {
        int o = o0 + tx * 4 + j;
        float bias = (o < 128) ? blow[o] : bhigh[o - 128];
        float4 v;
        v.x = acc[0][j] + bias;
        v.y = acc[1][j] + bias;
        v.z = acc[2][j] + bias;
        v.w = acc[3][j] + bias;
        *(float4*)&out[((size_t)b * COU + o) * NN + n0 + ty * 4] = v;
    }
}

extern "C" void kernel_launch(void* const* d_in, const int* in_sizes, int n_in,
                              void* d_out, int out_size, void* d_ws, size_t ws_size,
                              hipStream_t stream) {
    const float* xyz      = (const float*)d_in[0];
    const float* features = (const float*)d_in[1];
    const float* W_spec   = (const float*)d_in[2];
    const float* b_spec   = (const float*)d_in[3];
    const float* bn_gamma = (const float*)d_in[4];
    const float* bn_beta  = (const float*)d_in[5];
    const float* bn_mean  = (const float*)d_in[6];
    const float* bn_var   = (const float*)d_in[7];
    const float* W_low    = (const float*)d_in[8];
    const float* b_low    = (const float*)d_in[9];
    const float* W_high   = (const float*)d_in[10];
    const float* b_high   = (const float*)d_in[11];
    float* out = (float*)d_out;

    char* ws = (char*)d_ws;
    size_t off = 0;
    float* fT    = (float*)(ws + off); off += (size_t)BB * NN * CINC * 4;            // 8 MB
    float* specT = (float*)(ws + off); off += (size_t)BB * NN * CINC * 4;            // 8 MB
    float* g1T   = (float*)(ws + off); off += (size_t)BB * NN * COU  * 4;            // 16 MB
    int*   idx   = (int*)  (ws + off); off += (size_t)BB * NN * KNNK * 4;            // 1 MB
    int*   rcnt  = (int*)  (ws + off); off += (size_t)BB * NN * 4;                   // 64 KB
    int*   rev   = (int*)  (ws + off); off += (size_t)BB * NN * REVCAP * 4;          // 4 MB
    float* dinv  = (float*)(ws + off); off += (size_t)BB * NN * 4;                   // 64 KB
    unsigned long long* part = (unsigned long long*)(ws + off);
    off += (size_t)BB * NN * SEG * KNNK * 8;                                         // 16 MB

    hipMemsetAsync(rcnt, 0, (size_t)BB * NN * sizeof(int), stream);

    transpose_kernel<<<dim3(NN / 32, CINC / 32, BB), dim3(32, 8), 0, stream>>>(features, fT);
    knn_part_kernel<<<dim3(NN / 64, SEG / 4, BB), dim3(256), 0, stream>>>(xyz, part);
    knn_merge_kernel<<<dim3(BB * NN / 256), dim3(256), 0, stream>>>(part, idx, rcnt, rev);
    dinv_kernel<<<dim3(BB * NN / 256), dim3(256), 0, stream>>>(rcnt, dinv);
    spec_kernel<<<dim3(BB * NN), dim3(128), 0, stream>>>(fT, idx, rcnt, rev, dinv, specT);
    gemm1_kernel<<<dim3(NN / 64, COU / 64, BB), dim3(16, 16), 0, stream>>>(
        specT, W_spec, b_spec, bn_gamma, bn_beta, bn_mean, bn_var, g1T);
    gemm2_kernel<<<dim3(NN / 64, COU / 64, BB), dim3(16, 16), 0, stream>>>(
        g1T, W_low, b_low, W_high, b_high, out);
}

// Round 6
// 214.155 us; speedup vs baseline: 1.9912x; 1.5161x over previous
//
#include <hip/hip_runtime.h>
#include <math.h>

#define BB   8
#define NN   2048
#define CINC 128
#define COU  256
#define KNNK 16
#define REVCAP 64
#define SEG   8
#define SEGC  (NN / SEG)   // 256 candidates per segment

// ---- f64-encoded (dist,idx) keys: key = ordered_u32(dist)*2048 + idx  ----
// Max key < 2^43 < 2^53  => exactly representable; f64 order == u64 lexicographic
// (dist, idx) order => identical top-k semantics & tie-break to the u64 version.
// fmin/fmax compile to v_min_f64/v_max_f64 (1 inst vs cmp+2*cndmask for u64).

#define KTOP_DECL \
    double k0 = 1e300, k1 = 1e300, k2 = 1e300, k3 = 1e300,     \
           k4 = 1e300, k5 = 1e300, k6 = 1e300, k7 = 1e300,     \
           k8 = 1e300, k9 = 1e300, k10 = 1e300, k11 = 1e300,   \
           k12 = 1e300, k13 = 1e300, k14 = 1e300, k15 = 1e300;

// Branch-free sorted insert (drops old max): k_j = max(k_{j-1}, min(k_j, key)).
// No-op when key >= k15. Depth-2 dataflow, no divergence.
#define KTOP_INSERT(key_) {                 \
    k15 = fmax(k14, fmin(k15, (key_)));     \
    k14 = fmax(k13, fmin(k14, (key_)));     \
    k13 = fmax(k12, fmin(k13, (key_)));     \
    k12 = fmax(k11, fmin(k12, (key_)));     \
    k11 = fmax(k10, fmin(k11, (key_)));     \
    k10 = fmax(k9,  fmin(k10, (key_)));     \
    k9  = fmax(k8,  fmin(k9,  (key_)));     \
    k8  = fmax(k7,  fmin(k8,  (key_)));     \
    k7  = fmax(k6,  fmin(k7,  (key_)));     \
    k6  = fmax(k5,  fmin(k6,  (key_)));     \
    k5  = fmax(k4,  fmin(k5,  (key_)));     \
    k4  = fmax(k3,  fmin(k4,  (key_)));     \
    k3  = fmax(k2,  fmin(k3,  (key_)));     \
    k2  = fmax(k1,  fmin(k2,  (key_)));     \
    k1  = fmax(k0,  fmin(k1,  (key_)));     \
    k0  = fmin(k0, (key_));                 \
}

// ---------------- transpose features (B,C,N) -> fT (B,N,C) ----------------
__global__ __launch_bounds__(256) void transpose_kernel(const float* __restrict__ feat,
                                                        float* __restrict__ fT) {
    __shared__ float t[32][33];
    int b  = blockIdx.z;
    int n0 = blockIdx.x * 32, c0 = blockIdx.y * 32;
    int tx = threadIdx.x, ty = threadIdx.y;  // (32,8)
#pragma unroll
    for (int i = 0; i < 4; i++)
        t[ty + i * 8][tx] = feat[((size_t)b * CINC + c0 + ty + i * 8) * NN + n0 + tx];
    __syncthreads();
#pragma unroll
    for (int i = 0; i < 4; i++)
        fT[((size_t)b * NN + n0 + ty + i * 8) * CINC + c0 + tx] = t[tx][ty + i * 8];
}

// ---------------- KNN part: per-lane register top-16 over one segment ----------------
// lane = query, wave = one segment of 256 candidates (staged in LDS, broadcast reads).
// Distance arithmetic bit-identical to the verified round-1 kernel:
//   sq  = (x*x + y*y) + z*z                 (plain rn ops, no FMA)
//   dot = fma(z,z', fma(y,y', rn(x*x')))    (FMA chain)
//   dist = (sq_n + sq_m) - 2*dot            (plain rn ops)
__global__ __launch_bounds__(256) void knn_part_kernel(const float* __restrict__ xyz,
                                                       double* __restrict__ part) {
    __shared__ float4 cand[4][SEGC];
    int b = blockIdx.z;
    int lane = threadIdx.x & 63;
    int w = threadIdx.x >> 6;                 // wave id -> segment
    int q = blockIdx.x * 64 + lane;
    int s = blockIdx.y * 4 + w;

    const float* xb = xyz + (size_t)b * 3 * NN;

    // stage 4 segments (1024 candidates) cooperatively
    int base = blockIdx.y * (4 * SEGC);
    for (int t = threadIdx.x; t < 4 * SEGC; t += 256) {
        int m = base + t;
        float x = xb[m], y = xb[NN + m], z = xb[2 * NN + m];
        float sq = __fadd_rn(__fadd_rn(__fmul_rn(x, x), __fmul_rn(y, y)), __fmul_rn(z, z));
        cand[t >> 8][t & (SEGC - 1)] = make_float4(x, y, z, sq);
    }
    __syncthreads();

    float qx = xb[q], qy = xb[NN + q], qz = xb[2 * NN + q];
    float qsq = __fadd_rn(__fadd_rn(__fmul_rn(qx, qx), __fmul_rn(qy, qy)), __fmul_rn(qz, qz));

    KTOP_DECL

    double idxd = (double)(s * SEGC);        // exact integer accumulator
    for (int i = 0; i < SEGC; i++) {
        float4 c = cand[w][i];
        float dot = fmaf(qz, c.z, fmaf(qy, c.y, __fmul_rn(qx, c.x)));
        float d = __fsub_rn(__fadd_rn(qsq, c.w), __fmul_rn(2.0f, dot));
        unsigned int u = __float_as_uint(d);
        u = ((int)u < 0) ? ~u : (u | 0x80000000u);
        double key = fma((double)u, 2048.0, idxd);   // exact: < 2^43
        idxd += 1.0;
        KTOP_INSERT(key)
    }

    double* po = part + (((size_t)b * NN + q) * SEG + s) * KNNK;
    po[0] = k0;  po[1] = k1;  po[2] = k2;  po[3] = k3;
    po[4] = k4;  po[5] = k5;  po[6] = k6;  po[7] = k7;
    po[8] = k8;  po[9] = k9;  po[10] = k10; po[11] = k11;
    po[12] = k12; po[13] = k13; po[14] = k14; po[15] = k15;
}

// ---------------- KNN merge: fold 8 sorted 16-lists -> final top-16 ----------------
__global__ __launch_bounds__(256) void knn_merge_kernel(const double* __restrict__ part,
                                                        int* __restrict__ knn_idx,
                                                        int* __restrict__ revcnt,
                                                        int* __restrict__ rev) {
    int bq = blockIdx.x * 256 + threadIdx.x;   // b*NN + n
    int b = bq >> 11;
    int n = bq & (NN - 1);

    KTOP_DECL

    const double* pp = part + (size_t)bq * SEG * KNNK;
    for (int i = 0; i < SEG * KNNK; i++) {
        double key = pp[i];
        KTOP_INSERT(key)
    }

#define EMIT(j_, kreg_) {                                              \
        int m = (int)(((unsigned long long)(kreg_)) & 2047ull);        \
        knn_idx[(size_t)bq * KNNK + (j_)] = m;                         \
        int pos = atomicAdd(&revcnt[b * NN + m], 1);                   \
        if (pos < REVCAP) rev[((size_t)(b * NN + m)) * REVCAP + pos] = n; \
    }
    EMIT(0, k0)   EMIT(1, k1)   EMIT(2, k2)   EMIT(3, k3)
    EMIT(4, k4)   EMIT(5, k5)   EMIT(6, k6)   EMIT(7, k7)
    EMIT(8, k8)   EMIT(9, k9)   EMIT(10, k10) EMIT(11, k11)
    EMIT(12, k12) EMIT(13, k13) EMIT(14, k14) EMIT(15, k15)
#undef EMIT
}

// ---------------- dinv = rsqrt(D + 1e-6), D = 0.5*(K + indeg) ----------------
__global__ __launch_bounds__(256) void dinv_kernel(const int* __restrict__ revcnt,
                                                   float* __restrict__ dinv) {
    int i = blockIdx.x * 256 + threadIdx.x;
    if (i < BB * NN) {
        float D = 0.5f * (float)(KNNK + revcnt[i]);
        dinv[i] = 1.0f / sqrtf(D + 1e-6f);
    }
}

// ---------------- spec[c,n] = f[c,n] - d_n * sum_j 0.5*d_mj * f[c,mj] ----------------
__global__ __launch_bounds__(128) void spec_kernel(const float* __restrict__ fT,
                                                   const int* __restrict__ knn_idx,
                                                   const int* __restrict__ revcnt,
                                                   const int* __restrict__ rev,
                                                   const float* __restrict__ dinv,
                                                   float* __restrict__ specT) {
    __shared__ int ml[KNNK + REVCAP];
    __shared__ float wl[KNNK + REVCAP];
    __shared__ int s_cnt;

    int bn = blockIdx.x;           // b*NN + n
    int b = bn >> 11;
    int tid = threadIdx.x;

    if (tid == 0) {
        int c = revcnt[bn];
        s_cnt = c < REVCAP ? c : REVCAP;
    }
    __syncthreads();
    int cnt = s_cnt;
    if (tid < KNNK) ml[tid] = knn_idx[(size_t)bn * KNNK + tid];
    if (tid < cnt) ml[KNNK + tid] = rev[(size_t)bn * REVCAP + tid];
    __syncthreads();
    int total = KNNK + cnt;
    if (tid < total) wl[tid] = 0.5f * dinv[b * NN + ml[tid]];
    __syncthreads();

    float dn = dinv[bn];
    float acc = 0.0f;
    for (int j = 0; j < total; j++)
        acc = fmaf(wl[j], fT[((size_t)b * NN + ml[j]) * CINC + tid], acc);
    float f0 = fT[(size_t)bn * CINC + tid];
    specT[(size_t)bn * CINC + tid] = f0 - dn * acc;
}

// ---------------- GEMM1: g1 = gelu(bn(W_spec @ spec + b)) , layout (b,n,o) ----------------
__global__ __launch_bounds__(256) void gemm1_kernel(const float* __restrict__ specT,
                                                    const float* __restrict__ Wspec,
                                                    const float* __restrict__ bspec,
                                                    const float* __restrict__ gamma,
                                                    const float* __restrict__ beta,
                                                    const float* __restrict__ mean,
                                                    const float* __restrict__ var,
                                                    float* __restrict__ g1T) {
    __shared__ float Sa[64][65];
    __shared__ float Sb[64][65];
    int n0 = blockIdx.x * 64, o0 = blockIdx.y * 64, b = blockIdx.z;
    int tx = threadIdx.x, ty = threadIdx.y;
    int tid = ty * 16 + tx;

    float acc[4][4] = {};
    for (int kk = 0; kk < CINC; kk += 64) {
        __syncthreads();
        for (int i = tid; i < 64 * 64; i += 256) {
            int r = i >> 6, k = i & 63;
            Sa[r][k] = specT[((size_t)b * NN + n0 + r) * CINC + kk + k];
            Sb[r][k] = Wspec[(size_t)(o0 + r) * CINC + kk + k];
        }
        __syncthreads();
#pragma unroll 8
        for (int k = 0; k < 64; k++) {
            float a0 = Sa[ty * 4 + 0][k], a1 = Sa[ty * 4 + 1][k];
            float a2 = Sa[ty * 4 + 2][k], a3 = Sa[ty * 4 + 3][k];
            float w0 = Sb[tx * 4 + 0][k], w1 = Sb[tx * 4 + 1][k];
            float w2 = Sb[tx * 4 + 2][k], w3 = Sb[tx * 4 + 3][k];
            acc[0][0] = fmaf(a0, w0, acc[0][0]); acc[0][1] = fmaf(a0, w1, acc[0][1]);
            acc[0][2] = fmaf(a0, w2, acc[0][2]); acc[0][3] = fmaf(a0, w3, acc[0][3]);
            acc[1][0] = fmaf(a1, w0, acc[1][0]); acc[1][1] = fmaf(a1, w1, acc[1][1]);
            acc[1][2] = fmaf(a1, w2, acc[1][2]); acc[1][3] = fmaf(a1, w3, acc[1][3]);
            acc[2][0] = fmaf(a2, w0, acc[2][0]); acc[2][1] = fmaf(a2, w1, acc[2][1]);
            acc[2][2] = fmaf(a2, w2, acc[2][2]); acc[2][3] = fmaf(a2, w3, acc[2][3]);
            acc[3][0] = fmaf(a3, w0, acc[3][0]); acc[3][1] = fmaf(a3, w1, acc[3][1]);
            acc[3][2] = fmaf(a3, w2, acc[3][2]); acc[3][3] = fmaf(a3, w3, acc[3][3]);
        }
    }
#pragma unroll
    for (int j = 0; j < 4; j++) {
        int o = o0 + tx * 4 + j;
        float sc = 1.0f / sqrtf(var[o] + 1e-5f);
        float ga = gamma[o], be = beta[o], mu = mean[o], bs = bspec[o];
#pragma unroll
        for (int i = 0; i < 4; i++) {
            float y = acc[i][j] + bs;
            y = (y - mu) * sc;
            y = y * ga + be;
            float g = 0.5f * y * (1.0f + erff(y * 0.70710678118654752440f));
            g1T[((size_t)b * NN + n0 + ty * 4 + i) * COU + o] = g;
        }
    }
}

// ---------------- GEMM2: out[b,o,n] = W2[o,:] @ g1[b,n,:] + b2[o] ----------------
__global__ __launch_bounds__(256) void gemm2_kernel(const float* __restrict__ g1T,
                                                    const float* __restrict__ Wlow,
                                                    const float* __restrict__ blow,
                                                    const float* __restrict__ Whigh,
                                                    const float* __restrict__ bhigh,
                                                    float* __restrict__ out) {
    __shared__ float Ga[64][65];
    __shared__ float Wb[64][65];
    int n0 = blockIdx.x * 64, o0 = blockIdx.y * 64, b = blockIdx.z;
    int tx = threadIdx.x, ty = threadIdx.y;
    int tid = ty * 16 + tx;

    float acc[4][4] = {};
    for (int kk = 0; kk < COU; kk += 64) {
        __syncthreads();
        for (int i = tid; i < 64 * 64; i += 256) {
            int r = i >> 6, k = i & 63;
            Ga[r][k] = g1T[((size_t)b * NN + n0 + r) * COU + kk + k];
            int o = o0 + r;
            Wb[r][k] = (o < 128) ? Wlow[(size_t)o * COU + kk + k]
                                 : Whigh[(size_t)(o - 128) * COU + kk + k];
        }
        __syncthreads();
#pragma unroll 8
        for (int k = 0; k < 64; k++) {
            float a0 = Ga[ty * 4 + 0][k], a1 = Ga[ty * 4 + 1][k];
            float a2 = Ga[ty * 4 + 2][k], a3 = Ga[ty * 4 + 3][k];
            float w0 = Wb[tx * 4 + 0][k], w1 = Wb[tx * 4 + 1][k];
            float w2 = Wb[tx * 4 + 2][k], w3 = Wb[tx * 4 + 3][k];
            acc[0][0] = fmaf(a0, w0, acc[0][0]); acc[0][1] = fmaf(a0, w1, acc[0][1]);
            acc[0][2] = fmaf(a0, w2, acc[0][2]); acc[0][3] = fmaf(a0, w3, acc[0][3]);
            acc[1][0] = fmaf(a1, w0, acc[1][0]); acc[1][1] = fmaf(a1, w1, acc[1][1]);
            acc[1][2] = fmaf(a1, w2, acc[1][2]); acc[1][3] = fmaf(a1, w3, acc[1][3]);
            acc[2][0] = fmaf(a2, w0, acc[2][0]); acc[2][1] = fmaf(a2, w1, acc[2][1]);
            acc[2][2] = fmaf(a2, w2, acc[2][2]); acc[2][3] = fmaf(a2, w3, acc[2][3]);
            acc[3][0] = fmaf(a3, w0, acc[3][0]); acc[3][1] = fmaf(a3, w1, acc[3][1]);
            acc[3][2] = fmaf(a3, w2, acc[3][2]); acc[3][3] = fmaf(a3, w3, acc[3][3]);
        }
    }
#pragma unroll
    for (int j = 0; j < 4; j++) {
        int o = o0 + tx * 4 + j;
        float bias = (o < 128) ? blow[o] : bhigh[o - 128];
        float4 v;
        v.x = acc[0][j] + bias;
        v.y = acc[1][j] + bias;
        v.z = acc[2][j] + bias;
        v.w = acc[3][j] + bias;
        *(float4*)&out[((size_t)b * COU + o) * NN + n0 + ty * 4] = v;
    }
}

extern "C" void kernel_launch(void* const* d_in, const int* in_sizes, int n_in,
                              void* d_out, int out_size, void* d_ws, size_t ws_size,
                              hipStream_t stream) {
    const float* xyz      = (const float*)d_in[0];
    const float* features = (const float*)d_in[1];
    const float* W_spec   = (const float*)d_in[2];
    const float* b_spec   = (const float*)d_in[3];
    const float* bn_gamma = (const float*)d_in[4];
    const float* bn_beta  = (const float*)d_in[5];
    const float* bn_mean  = (const float*)d_in[6];
    const float* bn_var   = (const float*)d_in[7];
    const float* W_low    = (const float*)d_in[8];
    const float* b_low    = (const float*)d_in[9];
    const float* W_high   = (const float*)d_in[10];
    const float* b_high   = (const float*)d_in[11];
    float* out = (float*)d_out;

    char* ws = (char*)d_ws;
    size_t off = 0;
    float* fT    = (float*)(ws + off); off += (size_t)BB * NN * CINC * 4;            // 8 MB
    float* specT = (float*)(ws + off); off += (size_t)BB * NN * CINC * 4;            // 8 MB
    float* g1T   = (float*)(ws + off); off += (size_t)BB * NN * COU  * 4;            // 16 MB
    int*   idx   = (int*)  (ws + off); off += (size_t)BB * NN * KNNK * 4;            // 1 MB
    int*   rcnt  = (int*)  (ws + off); off += (size_t)BB * NN * 4;                   // 64 KB
    int*   rev   = (int*)  (ws + off); off += (size_t)BB * NN * REVCAP * 4;          // 4 MB
    float* dinv  = (float*)(ws + off); off += (size_t)BB * NN * 4;                   // 64 KB
    double* part = (double*)(ws + off);
    off += (size_t)BB * NN * SEG * KNNK * 8;                                         // 16 MB

    hipMemsetAsync(rcnt, 0, (size_t)BB * NN * sizeof(int), stream);

    transpose_kernel<<<dim3(NN / 32, CINC / 32, BB), dim3(32, 8), 0, stream>>>(features, fT);
    knn_part_kernel<<<dim3(NN / 64, SEG / 4, BB), dim3(256), 0, stream>>>(xyz, part);
    knn_merge_kernel<<<dim3(BB * NN / 256), dim3(256), 0, stream>>>(part, idx, rcnt, rev);
    dinv_kernel<<<dim3(BB * NN / 256), dim3(256), 0, stream>>>(rcnt, dinv);
    spec_kernel<<<dim3(BB * NN), dim3(128), 0, stream>>>(fT, idx, rcnt, rev, dinv, specT);
    gemm1_kernel<<<dim3(NN / 64, COU / 64, BB), dim3(16, 16), 0, stream>>>(
        specT, W_spec, b_spec, bn_gamma, bn_beta, bn_mean, bn_var, g1T);
    gemm2_kernel<<<dim3(NN / 64, COU / 64, BB), dim3(16, 16), 0, stream>>>(
        g1T, W_low, b_low, W_high, b_high, out);
}

// Round 8
// 164.342 us; speedup vs baseline: 2.5947x; 1.3031x over previous
//
#include <hip/hip_runtime.h>
#include <hip/hip_bf16.h>
#include <math.h>

#define BB   8
#define NN   2048
#define CINC 128
#define COU  256
#define KNNK 16
#define REVCAP 64
#define SEG   8
#define SEGC  (NN / SEG)   // 256 candidates per segment

typedef __bf16 bf16x8 __attribute__((ext_vector_type(8)));
typedef float  f32x4  __attribute__((ext_vector_type(4)));

// ---- f64-encoded (dist,idx) keys: key = ordered_u32(dist)*2048 + idx  ----
// Max key < 2^43 < 2^53 => exact; f64 order == u64 lexicographic (dist,idx).
#define KTOP_DECL \
    double k0 = 1e300, k1 = 1e300, k2 = 1e300, k3 = 1e300,     \
           k4 = 1e300, k5 = 1e300, k6 = 1e300, k7 = 1e300,     \
           k8 = 1e300, k9 = 1e300, k10 = 1e300, k11 = 1e300,   \
           k12 = 1e300, k13 = 1e300, k14 = 1e300, k15 = 1e300;

#define KTOP_INSERT(key_) {                 \
    k15 = fmax(k14, fmin(k15, (key_)));     \
    k14 = fmax(k13, fmin(k14, (key_)));     \
    k13 = fmax(k12, fmin(k13, (key_)));     \
    k12 = fmax(k11, fmin(k12, (key_)));     \
    k11 = fmax(k10, fmin(k11, (key_)));     \
    k10 = fmax(k9,  fmin(k10, (key_)));     \
    k9  = fmax(k8,  fmin(k9,  (key_)));     \
    k8  = fmax(k7,  fmin(k8,  (key_)));     \
    k7  = fmax(k6,  fmin(k7,  (key_)));     \
    k6  = fmax(k5,  fmin(k6,  (key_)));     \
    k5  = fmax(k4,  fmin(k5,  (key_)));     \
    k4  = fmax(k3,  fmin(k4,  (key_)));     \
    k3  = fmax(k2,  fmin(k3,  (key_)));     \
    k2  = fmax(k1,  fmin(k2,  (key_)));     \
    k1  = fmax(k0,  fmin(k1,  (key_)));     \
    k0  = fmin(k0, (key_));                 \
}

// ---------------- transpose features (B,C,N) -> fT (B,N,C) ----------------
__global__ __launch_bounds__(256) void transpose_kernel(const float* __restrict__ feat,
                                                        float* __restrict__ fT) {
    __shared__ float t[32][33];
    int b  = blockIdx.z;
    int n0 = blockIdx.x * 32, c0 = blockIdx.y * 32;
    int tx = threadIdx.x, ty = threadIdx.y;  // (32,8)
#pragma unroll
    for (int i = 0; i < 4; i++)
        t[ty + i * 8][tx] = feat[((size_t)b * CINC + c0 + ty + i * 8) * NN + n0 + tx];
    __syncthreads();
#pragma unroll
    for (int i = 0; i < 4; i++)
        fT[((size_t)b * NN + n0 + ty + i * 8) * CINC + c0 + tx] = t[tx][ty + i * 8];
}

// ---------------- prep: cast weights to bf16, concat W2 & bias ----------------
__global__ __launch_bounds__(256) void prep_kernel(const float* __restrict__ Wspec,
                                                   const float* __restrict__ Wlow,
                                                   const float* __restrict__ Whigh,
                                                   const float* __restrict__ blow,
                                                   const float* __restrict__ bhigh,
                                                   __bf16* __restrict__ WspecB,
                                                   __bf16* __restrict__ WcB,
                                                   float* __restrict__ bc) {
    int i = blockIdx.x * 256 + threadIdx.x;
    if (i < COU * CINC) WspecB[i] = (__bf16)Wspec[i];
    if (i < 128 * COU) {
        WcB[i] = (__bf16)Wlow[i];
        WcB[128 * COU + i] = (__bf16)Whigh[i];
    }
    if (i < 128) { bc[i] = blow[i]; bc[128 + i] = bhigh[i]; }
}

// ---------------- KNN part (unchanged from R6, verified) ----------------
__global__ __launch_bounds__(256) void knn_part_kernel(const float* __restrict__ xyz,
                                                       double* __restrict__ part) {
    __shared__ float4 cand[4][SEGC];
    int b = blockIdx.z;
    int lane = threadIdx.x & 63;
    int w = threadIdx.x >> 6;
    int q = blockIdx.x * 64 + lane;
    int s = blockIdx.y * 4 + w;

    const float* xb = xyz + (size_t)b * 3 * NN;

    int base = blockIdx.y * (4 * SEGC);
    for (int t = threadIdx.x; t < 4 * SEGC; t += 256) {
        int m = base + t;
        float x = xb[m], y = xb[NN + m], z = xb[2 * NN + m];
        float sq = __fadd_rn(__fadd_rn(__fmul_rn(x, x), __fmul_rn(y, y)), __fmul_rn(z, z));
        cand[t >> 8][t & (SEGC - 1)] = make_float4(x, y, z, sq);
    }
    __syncthreads();

    float qx = xb[q], qy = xb[NN + q], qz = xb[2 * NN + q];
    float qsq = __fadd_rn(__fadd_rn(__fmul_rn(qx, qx), __fmul_rn(qy, qy)), __fmul_rn(qz, qz));

    KTOP_DECL

    double idxd = (double)(s * SEGC);
    for (int i = 0; i < SEGC; i++) {
        float4 c = cand[w][i];
        float dot = fmaf(qz, c.z, fmaf(qy, c.y, __fmul_rn(qx, c.x)));
        float d = __fsub_rn(__fadd_rn(qsq, c.w), __fmul_rn(2.0f, dot));
        unsigned int u = __float_as_uint(d);
        u = ((int)u < 0) ? ~u : (u | 0x80000000u);
        double key = fma((double)u, 2048.0, idxd);
        idxd += 1.0;
        KTOP_INSERT(key)
    }

    double* po = part + (((size_t)b * NN + q) * SEG + s) * KNNK;
    po[0] = k0;  po[1] = k1;  po[2] = k2;  po[3] = k3;
    po[4] = k4;  po[5] = k5;  po[6] = k6;  po[7] = k7;
    po[8] = k8;  po[9] = k9;  po[10] = k10; po[11] = k11;
    po[12] = k12; po[13] = k13; po[14] = k14; po[15] = k15;
}

// ---------------- KNN merge (unchanged from R6) ----------------
__global__ __launch_bounds__(256) void knn_merge_kernel(const double* __restrict__ part,
                                                        int* __restrict__ knn_idx,
                                                        int* __restrict__ revcnt,
                                                        int* __restrict__ rev) {
    int bq = blockIdx.x * 256 + threadIdx.x;
    int b = bq >> 11;
    int n = bq & (NN - 1);

    KTOP_DECL

    const double* pp = part + (size_t)bq * SEG * KNNK;
    for (int i = 0; i < SEG * KNNK; i++) {
        double key = pp[i];
        KTOP_INSERT(key)
    }

#define EMIT(j_, kreg_) {                                              \
        int m = (int)(((unsigned long long)(kreg_)) & 2047ull);        \
        knn_idx[(size_t)bq * KNNK + (j_)] = m;                         \
        int pos = atomicAdd(&revcnt[b * NN + m], 1);                   \
        if (pos < REVCAP) rev[((size_t)(b * NN + m)) * REVCAP + pos] = n; \
    }
    EMIT(0, k0)   EMIT(1, k1)   EMIT(2, k2)   EMIT(3, k3)
    EMIT(4, k4)   EMIT(5, k5)   EMIT(6, k6)   EMIT(7, k7)
    EMIT(8, k8)   EMIT(9, k9)   EMIT(10, k10) EMIT(11, k11)
    EMIT(12, k12) EMIT(13, k13) EMIT(14, k14) EMIT(15, k15)
#undef EMIT
}

// ---------------- dinv = rsqrt(D + 1e-6), D = 0.5*(K + indeg) ----------------
__global__ __launch_bounds__(256) void dinv_kernel(const int* __restrict__ revcnt,
                                                   float* __restrict__ dinv) {
    int i = blockIdx.x * 256 + threadIdx.x;
    if (i < BB * NN) {
        float D = 0.5f * (float)(KNNK + revcnt[i]);
        dinv[i] = 1.0f / sqrtf(D + 1e-6f);
    }
}

// ---------------- spec: f32 compute, bf16 output ----------------
__global__ __launch_bounds__(128) void spec_kernel(const float* __restrict__ fT,
                                                   const int* __restrict__ knn_idx,
                                                   const int* __restrict__ revcnt,
                                                   const int* __restrict__ rev,
                                                   const float* __restrict__ dinv,
                                                   __bf16* __restrict__ specB) {
    __shared__ int ml[KNNK + REVCAP];
    __shared__ float wl[KNNK + REVCAP];
    __shared__ int s_cnt;

    int bn = blockIdx.x;           // b*NN + n
    int b = bn >> 11;
    int tid = threadIdx.x;

    if (tid == 0) {
        int c = revcnt[bn];
        s_cnt = c < REVCAP ? c : REVCAP;
    }
    __syncthreads();
    int cnt = s_cnt;
    if (tid < KNNK) ml[tid] = knn_idx[(size_t)bn * KNNK + tid];
    if (tid < cnt) ml[KNNK + tid] = rev[(size_t)bn * REVCAP + tid];
    __syncthreads();
    int total = KNNK + cnt;
    if (tid < total) wl[tid] = 0.5f * dinv[b * NN + ml[tid]];
    __syncthreads();

    float dn = dinv[bn];
    float acc = 0.0f;
    for (int j = 0; j < total; j++)
        acc = fmaf(wl[j], fT[((size_t)b * NN + ml[j]) * CINC + tid], acc);
    float f0 = fT[(size_t)bn * CINC + tid];
    specB[(size_t)bn * CINC + tid] = (__bf16)(f0 - dn * acc);
}

// ---------------- GEMM1 (MFMA): g1 = gelu(bn(spec @ Wspec^T + b)) ----------------
// out1[n,o] = sum_c spec[n][c] * Wspec[o][c]  -> A = spec rows (M=n), B = Wspec rows (N=o)
// mfma_f32_16x16x32_bf16: frags k-contiguous 16B/lane; D: col=lane&15 (N), row=(lane>>4)*4+j (M)
__global__ __launch_bounds__(256) void gemm1_mfma(const __bf16* __restrict__ specB,
                                                  const __bf16* __restrict__ WspecB,
                                                  const float* __restrict__ bspec,
                                                  const float* __restrict__ gamma,
                                                  const float* __restrict__ beta,
                                                  const float* __restrict__ mean,
                                                  const float* __restrict__ var,
                                                  __bf16* __restrict__ g1B) {
    int b  = blockIdx.y;
    int n0 = blockIdx.x * 64;
    int w = threadIdx.x >> 6, lane = threadIdx.x & 63;
    int o0 = w * 64;                       // 4 waves tile o = 0..255
    int lr = lane & 15, lk = (lane >> 4) * 8;

    f32x4 acc[4][4] = {};
    const __bf16* As = specB + ((size_t)b * NN + n0 + lr) * CINC + lk;
    const __bf16* Bs = WspecB + (size_t)(o0 + lr) * CINC + lk;
#pragma unroll
    for (int kk = 0; kk < CINC; kk += 32) {
        bf16x8 a[4], bb[4];
#pragma unroll
        for (int m = 0; m < 4; m++)
            a[m] = *(const bf16x8*)(As + (size_t)(m * 16) * CINC + kk);
#pragma unroll
        for (int n = 0; n < 4; n++)
            bb[n] = *(const bf16x8*)(Bs + (size_t)(n * 16) * CINC + kk);
#pragma unroll
        for (int m = 0; m < 4; m++)
#pragma unroll
            for (int n = 0; n < 4; n++)
                acc[m][n] = __builtin_amdgcn_mfma_f32_16x16x32_bf16(a[m], bb[n], acc[m][n], 0, 0, 0);
    }

    int rb = (lane >> 4) * 4;
#pragma unroll
    for (int n = 0; n < 4; n++) {
        int o = o0 + n * 16 + lr;
        float sc = 1.0f / sqrtf(var[o] + 1e-5f);
        float ga = gamma[o], be = beta[o], mu = mean[o], bs = bspec[o];
#pragma unroll
        for (int m = 0; m < 4; m++) {
#pragma unroll
            for (int j = 0; j < 4; j++) {
                int nrow = n0 + m * 16 + rb + j;
                float y = acc[m][n][j] + bs;
                y = (y - mu) * sc;
                y = y * ga + be;
                float g = 0.5f * y * (1.0f + erff(y * 0.70710678118654752440f));
                g1B[((size_t)b * NN + nrow) * COU + o] = (__bf16)g;
            }
        }
    }
}

// ---------------- GEMM2 (MFMA): out[b,o,n] = Wc[o,:] @ g1[b,n,:] + bc[o] ----------------
// A = Wc rows (M=o), B = g1 rows (N=n); writes f32 out, 16-lane-contiguous in n.
__global__ __launch_bounds__(256) void gemm2_mfma(const __bf16* __restrict__ g1B,
                                                  const __bf16* __restrict__ WcB,
                                                  const float* __restrict__ bc,
                                                  float* __restrict__ out) {
    int b  = blockIdx.z;
    int n0 = blockIdx.x * 256;
    int o0 = blockIdx.y * 64;
    int w = threadIdx.x >> 6, lane = threadIdx.x & 63;
    int n0w = n0 + w * 64;                 // 4 waves tile n
    int lr = lane & 15, lk = (lane >> 4) * 8;

    f32x4 acc[4][4] = {};
    const __bf16* As = WcB + (size_t)(o0 + lr) * COU + lk;
    const __bf16* Bs = g1B + ((size_t)b * NN + n0w + lr) * COU + lk;
#pragma unroll
    for (int kk = 0; kk < COU; kk += 32) {
        bf16x8 a[4], bb[4];
#pragma unroll
        for (int m = 0; m < 4; m++)
            a[m] = *(const bf16x8*)(As + (size_t)(m * 16) * COU + kk);
#pragma unroll
        for (int n = 0; n < 4; n++)
            bb[n] = *(const bf16x8*)(Bs + (size_t)(n * 16) * COU + kk);
#pragma unroll
        for (int m = 0; m < 4; m++)
#pragma unroll
            for (int n = 0; n < 4; n++)
                acc[m][n] = __builtin_amdgcn_mfma_f32_16x16x32_bf16(a[m], bb[n], acc[m][n], 0, 0, 0);
    }

    int rb = (lane >> 4) * 4;
#pragma unroll
    for (int m = 0; m < 4; m++) {
#pragma unroll
        for (int j = 0; j < 4; j++) {
            int o = o0 + m * 16 + rb + j;
            float bias = bc[o];
#pragma unroll
            for (int n = 0; n < 4; n++) {
                int ncol = n0w + n * 16 + lr;
                out[((size_t)b * COU + o) * NN + ncol] = acc[m][n][j] + bias;
            }
        }
    }
}

extern "C" void kernel_launch(void* const* d_in, const int* in_sizes, int n_in,
                              void* d_out, int out_size, void* d_ws, size_t ws_size,
                              hipStream_t stream) {
    const float* xyz      = (const float*)d_in[0];
    const float* features = (const float*)d_in[1];
    const float* W_spec   = (const float*)d_in[2];
    const float* b_spec   = (const float*)d_in[3];
    const float* bn_gamma = (const float*)d_in[4];
    const float* bn_beta  = (const float*)d_in[5];
    const float* bn_mean  = (const float*)d_in[6];
    const float* bn_var   = (const float*)d_in[7];
    const float* W_low    = (const float*)d_in[8];
    const float* b_low    = (const float*)d_in[9];
    const float* W_high   = (const float*)d_in[10];
    const float* b_high   = (const float*)d_in[11];
    float* out = (float*)d_out;

    char* ws = (char*)d_ws;
    size_t off = 0;
    float*  fT    = (float*)(ws + off);  off += (size_t)BB * NN * CINC * 4;      // 8 MB
    __bf16* specB = (__bf16*)(ws + off); off += (size_t)BB * NN * CINC * 2;      // 4 MB
    __bf16* g1B   = (__bf16*)(ws + off); off += (size_t)BB * NN * COU  * 2;      // 8 MB
    int*    idx   = (int*)(ws + off);    off += (size_t)BB * NN * KNNK * 4;      // 1 MB
    int*    rcnt  = (int*)(ws + off);    off += (size_t)BB * NN * 4;             // 64 KB
    int*    rev   = (int*)(ws + off);    off += (size_t)BB * NN * REVCAP * 4;    // 4 MB
    float*  dinv  = (float*)(ws + off);  off += (size_t)BB * NN * 4;             // 64 KB
    double* part  = (double*)(ws + off); off += (size_t)BB * NN * SEG * KNNK * 8;// 16 MB
    __bf16* WspecB= (__bf16*)(ws + off); off += (size_t)COU * CINC * 2;          // 64 KB
    __bf16* WcB   = (__bf16*)(ws + off); off += (size_t)COU * COU * 2;           // 128 KB
    float*  bc    = (float*)(ws + off);  off += (size_t)COU * 4;                 // 1 KB

    hipMemsetAsync(rcnt, 0, (size_t)BB * NN * sizeof(int), stream);

    prep_kernel<<<dim3((COU * CINC + 255) / 256), dim3(256), 0, stream>>>(
        W_spec, W_low, W_high, b_low, b_high, WspecB, WcB, bc);
    transpose_kernel<<<dim3(NN / 32, CINC / 32, BB), dim3(32, 8), 0, stream>>>(features, fT);
    knn_part_kernel<<<dim3(NN / 64, SEG / 4, BB), dim3(256), 0, stream>>>(xyz, part);
    knn_merge_kernel<<<dim3(BB * NN / 256), dim3(256), 0, stream>>>(part, idx, rcnt, rev);
    dinv_kernel<<<dim3(BB * NN / 256), dim3(256), 0, stream>>>(rcnt, dinv);
    spec_kernel<<<dim3(BB * NN), dim3(128), 0, stream>>>(fT, idx, rcnt, rev, dinv, specB);
    gemm1_mfma<<<dim3(NN / 64, BB), dim3(256), 0, stream>>>(
        specB, WspecB, b_spec, bn_gamma, bn_beta, bn_mean, bn_var, g1B);
    gemm2_mfma<<<dim3(NN / 256, COU / 64, BB), dim3(256), 0, stream>>>(g1B, WcB, bc, out);
}